// Round 1
// baseline (308.334 us; speedup 1.0000x reference)
//
#include <hip/hip_runtime.h>
#include <math.h>

#define B 16
#define C 256
#define HW 4096              // 64*64
#define EPSE 1e-9f
#define NTHREADS 256

// ---------------------------------------------------------------------------
// Kernel 1: pooled[f][b][c] = mean over HW of feat[b][c][:]
// grid = 2*B*C blocks, 256 threads
// ---------------------------------------------------------------------------
__global__ void k_pooled(const float* __restrict__ vis,
                         const float* __restrict__ txt,
                         float* __restrict__ pooled) {
    int blk = blockIdx.x;              // [0, 2*B*C)
    int f   = blk >> 12;               // / (B*C)
    int bc  = blk & (B * C - 1);
    const float* src = (f == 0 ? vis : txt) + (size_t)bc * HW;
    const float4* s4 = (const float4*)src;

    float s = 0.f;
    for (int i = threadIdx.x; i < HW / 4; i += NTHREADS) {
        float4 v = s4[i];
        s += v.x + v.y + v.z + v.w;
    }
    // wave(64) reduce + cross-wave via LDS
    for (int off = 32; off > 0; off >>= 1) s += __shfl_down(s, off);
    __shared__ float sm[4];
    if ((threadIdx.x & 63) == 0) sm[threadIdx.x >> 6] = s;
    __syncthreads();
    if (threadIdx.x == 0) {
        float tot = sm[0] + sm[1] + sm[2] + sm[3];
        pooled[blk] = tot * (1.0f / HW);
    }
}

// ---------------------------------------------------------------------------
// Kernel 2: tiny MLP  cw = sigmoid(relu(pooled@w1 + b1)@w2 + b2)
// grid = 2 blocks (one per feat), 256 threads
// ---------------------------------------------------------------------------
__global__ void k_mlp(const float* __restrict__ pooled,
                      const float* __restrict__ w1, const float* __restrict__ b1,
                      const float* __restrict__ w2, const float* __restrict__ b2,
                      float* __restrict__ cw) {
    __shared__ float pl[B * C];     // 16 KB
    __shared__ float h[B * 64];     // 4 KB
    int f = blockIdx.x;
    const float* P = pooled + f * B * C;
    for (int i = threadIdx.x; i < B * C; i += NTHREADS) pl[i] = P[i];
    __syncthreads();
    // layer 1: [B,C] @ [C,64] -> relu -> h[B,64]
    for (int o = threadIdx.x; o < B * 64; o += NTHREADS) {
        int b = o >> 6, j = o & 63;
        float acc = b1[j];
        for (int c = 0; c < C; ++c) acc = fmaf(pl[b * C + c], w1[c * 64 + j], acc);
        h[o] = fmaxf(acc, 0.f);
    }
    __syncthreads();
    // layer 2: [B,64] @ [64,C] -> sigmoid -> cw[B,C]
    for (int o = threadIdx.x; o < B * C; o += NTHREADS) {
        int b = o >> 8, c2 = o & 255;
        float acc = b2[c2];
        for (int j = 0; j < 64; ++j) acc = fmaf(h[b * 64 + j], w2[j * 256 + c2], acc);
        cw[f * B * C + o] = 1.f / (1.f + expf(-acc));
    }
}

// ---------------------------------------------------------------------------
// Kernel 3: se[f][b][hw] = sum_c ent(feat[b][c][hw]) * cw[f][b][c]
// grid = 2*B*16 = 512 blocks, 256 threads (each block: one 256-wide hw tile)
// ---------------------------------------------------------------------------
__global__ void k_se(const float* __restrict__ vis,
                     const float* __restrict__ txt,
                     const float* __restrict__ cw,
                     float* __restrict__ se) {
    __shared__ float cwl[C];
    int bx   = blockIdx.x;             // [0, 512)
    int f    = bx >> 8;
    int b    = (bx >> 4) & 15;
    int tile = bx & 15;
    const float* src = (f == 0 ? vis : txt)
                       + (size_t)b * C * HW + tile * 256 + threadIdx.x;
    for (int i = threadIdx.x; i < C; i += NTHREADS)
        cwl[i] = cw[f * B * C + b * C + i];
    __syncthreads();

    float acc = 0.f;
    for (int c = 0; c < C; ++c) {
        float x = src[(size_t)c * HW];
        float p = 1.f / (1.f + __expf(-x));
        float ent = __logf(p + EPSE) - (1.f - p) * __logf(1.f - p + EPSE);
        acc = fmaf(ent, cwl[c], acc);
    }
    se[f * B * HW + b * HW + tile * 256 + threadIdx.x] = acc;
}

// ---------------------------------------------------------------------------
// Kernel 4: per-(f,b) stats over se: inv_norm = 1/max(||se||2, 1e-12),
//           thr = 0.5 * mean(se)   (scale-invariant mask threshold)
// grid = 2*B = 32 blocks, 256 threads
// ---------------------------------------------------------------------------
__global__ void k_stats(const float* __restrict__ se,
                        float* __restrict__ inv_norm,
                        float* __restrict__ thr) {
    int fb = blockIdx.x;               // [0, 32)
    const float4* s4 = (const float4*)(se + fb * HW);
    float s = 0.f, ss = 0.f;
    for (int i = threadIdx.x; i < HW / 4; i += NTHREADS) {
        float4 v = s4[i];
        s  += v.x + v.y + v.z + v.w;
        ss = fmaf(v.x, v.x, ss); ss = fmaf(v.y, v.y, ss);
        ss = fmaf(v.z, v.z, ss); ss = fmaf(v.w, v.w, ss);
    }
    for (int off = 32; off > 0; off >>= 1) {
        s  += __shfl_down(s, off);
        ss += __shfl_down(ss, off);
    }
    __shared__ float sm[8];
    if ((threadIdx.x & 63) == 0) {
        sm[(threadIdx.x >> 6) * 2]     = s;
        sm[(threadIdx.x >> 6) * 2 + 1] = ss;
    }
    __syncthreads();
    if (threadIdx.x == 0) {
        float st = sm[0] + sm[2] + sm[4] + sm[6];
        float sst = sm[1] + sm[3] + sm[5] + sm[7];
        inv_norm[fb] = 1.f / fmaxf(sqrtf(sst), 1e-12f);
        thr[fb]      = 0.5f * (st * (1.0f / HW));
    }
}

// ---------------------------------------------------------------------------
// Kernel 5: write normalized entropy maps to d_out and build selector bytes
// grid = B*HW/256 = 256 blocks, 256 threads
// ---------------------------------------------------------------------------
__global__ void k_selwrite(const float* __restrict__ se,
                           const float* __restrict__ inv_norm,
                           const float* __restrict__ thr,
                           float* __restrict__ out_ent_vis,
                           float* __restrict__ out_ent_text,
                           unsigned char* __restrict__ sel) {
    int id = blockIdx.x * NTHREADS + threadIdx.x;   // [0, B*HW)
    int b  = id >> 12;
    float sv = se[id];              // f=0 slab
    float st = se[B * HW + id];     // f=1 slab
    out_ent_vis[id]  = sv * inv_norm[b];
    out_ent_text[id] = st * inv_norm[B + b];
    bool vl = sv < thr[b];
    bool tl = st < thr[B + b];
    sel[id] = vl ? (unsigned char)1 : (tl ? (unsigned char)2 : (unsigned char)0);
}

// ---------------------------------------------------------------------------
// Kernel 6: enhanced = sel==1 ? vis : (sel==2 ? text : 0)
// grid-stride over float4s
// ---------------------------------------------------------------------------
__global__ void k_final(const float* __restrict__ vis,
                        const float* __restrict__ txt,
                        const unsigned char* __restrict__ sel,
                        float* __restrict__ out) {
    const int total4 = B * C * HW / 4;     // 4,194,304
    int stride = gridDim.x * blockDim.x;
    for (int i = blockIdx.x * blockDim.x + threadIdx.x; i < total4; i += stride) {
        float4 v = ((const float4*)vis)[i];
        float4 t = ((const float4*)txt)[i];
        int idx = i << 2;                  // float index
        int b   = idx >> 20;               // / (C*HW)
        int hw  = idx & (HW - 1);
        uchar4 s = *(const uchar4*)(sel + (b << 12) + hw);
        float4 o;
        o.x = (s.x == 1) ? v.x : ((s.x == 2) ? t.x : 0.f);
        o.y = (s.y == 1) ? v.y : ((s.y == 2) ? t.y : 0.f);
        o.z = (s.z == 1) ? v.z : ((s.z == 2) ? t.z : 0.f);
        o.w = (s.w == 1) ? v.w : ((s.w == 2) ? t.w : 0.f);
        ((float4*)out)[i] = o;
    }
}

// ---------------------------------------------------------------------------
extern "C" void kernel_launch(void* const* d_in, const int* in_sizes, int n_in,
                              void* d_out, int out_size, void* d_ws, size_t ws_size,
                              hipStream_t stream) {
    const float* vis = (const float*)d_in[0];
    const float* txt = (const float*)d_in[1];
    const float* w1  = (const float*)d_in[2];
    const float* b1  = (const float*)d_in[3];
    const float* w2  = (const float*)d_in[4];
    const float* b2  = (const float*)d_in[5];

    float* out_enh      = (float*)d_out;                 // B*C*HW
    float* out_ent_vis  = out_enh + (size_t)B * C * HW;  // B*HW
    float* out_ent_text = out_ent_vis + B * HW;          // B*HW

    // workspace layout (floats)
    float* ws       = (float*)d_ws;
    float* pooled   = ws;                 //  8192
    float* cw       = ws + 8192;          //  8192
    float* se       = ws + 16384;         // 131072
    float* inv_norm = ws + 147456;        //     32
    float* thr      = ws + 147488;        //     32
    unsigned char* sel = (unsigned char*)(ws + 147520);  // 65536 bytes

    k_pooled  <<<2 * B * C, NTHREADS, 0, stream>>>(vis, txt, pooled);
    k_mlp     <<<2,         NTHREADS, 0, stream>>>(pooled, w1, b1, w2, b2, cw);
    k_se      <<<2 * B * 16, NTHREADS, 0, stream>>>(vis, txt, cw, se);
    k_stats   <<<2 * B,     NTHREADS, 0, stream>>>(se, inv_norm, thr);
    k_selwrite<<<B * HW / NTHREADS, NTHREADS, 0, stream>>>(se, inv_norm, thr,
                                                           out_ent_vis, out_ent_text, sel);
    k_final   <<<2048,      NTHREADS, 0, stream>>>(vis, txt, sel, out_enh);
}

// Round 2
// 267.454 us; speedup vs baseline: 1.1528x; 1.1528x over previous
//
#include <hip/hip_runtime.h>
#include <math.h>

#define B 16
#define C 256
#define HW 4096              // 64*64
#define EPSE 1e-9f
#define NTHREADS 256
#define CCHUNK 32            // channels per k_se block (8 chunks)

__device__ __forceinline__ float fast_rcp(float x) { return __builtin_amdgcn_rcpf(x); }

// ent(x) = log(p+eps) - (1-p)*log(1-p+eps), p = sigmoid(x)
__device__ __forceinline__ float entf(float x) {
    float e  = __expf(-x);                    // v_mul + v_exp
    float p  = fast_rcp(1.f + e);             // v_add + v_rcp
    float l1 = __logf(p + EPSE);              // v_add + v_log + v_mul
    float q  = 1.f - p;                       // v_sub
    float l2 = __logf(q + EPSE);              // v_add + v_log + v_mul
    return fmaf(-q, l2, l1);                  // v_fma
}

// ---------------------------------------------------------------------------
// Kernel 1: pooled[f][b][c] = mean over HW of feat[b][c][:]
//           + first 128 blocks zero the se accumulator (ws is poisoned 0xAA)
// grid = 2*B*C = 8192 blocks, 256 threads
// ---------------------------------------------------------------------------
__global__ void k_pooled(const float* __restrict__ vis,
                         const float* __restrict__ txt,
                         float* __restrict__ pooled,
                         float* __restrict__ se) {
    int blk = blockIdx.x;              // [0, 2*B*C)
    if (blk < 128) {                   // zero se: 128 blocks * 1024 floats = 131072
        float4 z = make_float4(0.f, 0.f, 0.f, 0.f);
        ((float4*)se)[blk * NTHREADS + threadIdx.x] = z;
    }
    int f   = blk >> 12;               // / (B*C)
    int bc  = blk & (B * C - 1);
    const float* src = (f == 0 ? vis : txt) + (size_t)bc * HW;
    const float4* s4 = (const float4*)src;

    float s = 0.f;
    #pragma unroll
    for (int i = threadIdx.x; i < HW / 4; i += NTHREADS) {
        float4 v = s4[i];
        s += v.x + v.y + v.z + v.w;
    }
    for (int off = 32; off > 0; off >>= 1) s += __shfl_down(s, off);
    __shared__ float sm[4];
    if ((threadIdx.x & 63) == 0) sm[threadIdx.x >> 6] = s;
    __syncthreads();
    if (threadIdx.x == 0) {
        float tot = sm[0] + sm[1] + sm[2] + sm[3];
        pooled[blk] = tot * (1.0f / HW);
    }
}

// ---------------------------------------------------------------------------
// Kernel 2: tiny MLP  cw = sigmoid(relu(pooled@w1 + b1)@w2 + b2)
// grid = 2 blocks (one per feat), 256 threads
// ---------------------------------------------------------------------------
__global__ void k_mlp(const float* __restrict__ pooled,
                      const float* __restrict__ w1, const float* __restrict__ b1,
                      const float* __restrict__ w2, const float* __restrict__ b2,
                      float* __restrict__ cw) {
    __shared__ float pl[B * C];     // 16 KB
    __shared__ float h[B * 64];     // 4 KB
    int f = blockIdx.x;
    const float* P = pooled + f * B * C;
    for (int i = threadIdx.x; i < B * C; i += NTHREADS) pl[i] = P[i];
    __syncthreads();
    for (int o = threadIdx.x; o < B * 64; o += NTHREADS) {
        int b = o >> 6, j = o & 63;
        float acc = b1[j];
        for (int c = 0; c < C; ++c) acc = fmaf(pl[b * C + c], w1[c * 64 + j], acc);
        h[o] = fmaxf(acc, 0.f);
    }
    __syncthreads();
    for (int o = threadIdx.x; o < B * C; o += NTHREADS) {
        int b = o >> 8, c2 = o & 255;
        float acc = b2[c2];
        for (int j = 0; j < 64; ++j) acc = fmaf(h[b * 64 + j], w2[j * 256 + c2], acc);
        cw[f * B * C + o] = fast_rcp(1.f + __expf(-acc));
    }
}

// ---------------------------------------------------------------------------
// Kernel 3: se[f][b][hw] += sum_{c in chunk} ent(feat[b][c][hw]) * cw[f][b][c]
// grid = 2 * B * 4 hw-tiles * 8 c-chunks = 1024 blocks, 256 threads
// Each thread: one float4 of hw (16 B/lane loads), 32-channel partial sum,
// 4 atomicAdds into L2-resident se (512 KB).
// ---------------------------------------------------------------------------
__global__ void k_se(const float* __restrict__ vis,
                     const float* __restrict__ txt,
                     const float* __restrict__ cw,
                     float* __restrict__ se) {
    int bx   = blockIdx.x;             // [0, 1024)
    int cc   = bx & 7;                 // c-chunk
    int tile = (bx >> 3) & 3;          // 1024-hw tile
    int b    = (bx >> 5) & 15;
    int f    = bx >> 9;
    const float* src = (f == 0 ? vis : txt)
                       + (size_t)b * C * HW + (size_t)cc * CCHUNK * HW
                       + tile * 1024 + threadIdx.x * 4;

    __shared__ float cwl[CCHUNK];
    if (threadIdx.x < CCHUNK)
        cwl[threadIdx.x] = cw[f * B * C + b * C + cc * CCHUNK + threadIdx.x];
    __syncthreads();

    float4 acc = make_float4(0.f, 0.f, 0.f, 0.f);
    #pragma unroll 4
    for (int c = 0; c < CCHUNK; ++c) {
        float4 x = *(const float4*)(src + (size_t)c * HW);
        float w = cwl[c];
        acc.x = fmaf(entf(x.x), w, acc.x);
        acc.y = fmaf(entf(x.y), w, acc.y);
        acc.z = fmaf(entf(x.z), w, acc.z);
        acc.w = fmaf(entf(x.w), w, acc.w);
    }
    float* dst = se + (f * B + b) * HW + tile * 1024 + threadIdx.x * 4;
    atomicAdd(dst + 0, acc.x);
    atomicAdd(dst + 1, acc.y);
    atomicAdd(dst + 2, acc.z);
    atomicAdd(dst + 3, acc.w);
}

// ---------------------------------------------------------------------------
// Kernel 4: per-(f,b) stats over se: inv_norm = 1/max(||se||2, 1e-12),
//           thr = 0.5 * mean(se)   (scale-invariant mask threshold)
// grid = 2*B = 32 blocks, 256 threads
// ---------------------------------------------------------------------------
__global__ void k_stats(const float* __restrict__ se,
                        float* __restrict__ inv_norm,
                        float* __restrict__ thr) {
    int fb = blockIdx.x;               // [0, 32)
    const float4* s4 = (const float4*)(se + fb * HW);
    float s = 0.f, ss = 0.f;
    #pragma unroll
    for (int i = threadIdx.x; i < HW / 4; i += NTHREADS) {
        float4 v = s4[i];
        s  += v.x + v.y + v.z + v.w;
        ss = fmaf(v.x, v.x, ss); ss = fmaf(v.y, v.y, ss);
        ss = fmaf(v.z, v.z, ss); ss = fmaf(v.w, v.w, ss);
    }
    for (int off = 32; off > 0; off >>= 1) {
        s  += __shfl_down(s, off);
        ss += __shfl_down(ss, off);
    }
    __shared__ float sm[8];
    if ((threadIdx.x & 63) == 0) {
        sm[(threadIdx.x >> 6) * 2]     = s;
        sm[(threadIdx.x >> 6) * 2 + 1] = ss;
    }
    __syncthreads();
    if (threadIdx.x == 0) {
        float st  = sm[0] + sm[2] + sm[4] + sm[6];
        float sst = sm[1] + sm[3] + sm[5] + sm[7];
        inv_norm[fb] = 1.f / fmaxf(sqrtf(sst), 1e-12f);
        thr[fb]      = 0.5f * (st * (1.0f / HW));
    }
}

// ---------------------------------------------------------------------------
// Kernel 5: write normalized entropy maps to d_out and build selector bytes
// grid = B*HW/256 = 256 blocks, 256 threads
// ---------------------------------------------------------------------------
__global__ void k_selwrite(const float* __restrict__ se,
                           const float* __restrict__ inv_norm,
                           const float* __restrict__ thr,
                           float* __restrict__ out_ent_vis,
                           float* __restrict__ out_ent_text,
                           unsigned char* __restrict__ sel) {
    int id = blockIdx.x * NTHREADS + threadIdx.x;   // [0, B*HW)
    int b  = id >> 12;
    float sv = se[id];              // f=0 slab
    float st = se[B * HW + id];     // f=1 slab
    out_ent_vis[id]  = sv * inv_norm[b];
    out_ent_text[id] = st * inv_norm[B + b];
    bool vl = sv < thr[b];
    bool tl = st < thr[B + b];
    sel[id] = vl ? (unsigned char)1 : (tl ? (unsigned char)2 : (unsigned char)0);
}

// ---------------------------------------------------------------------------
// Kernel 6: enhanced = sel==1 ? vis : (sel==2 ? text : 0)
// grid-stride over float4s
// ---------------------------------------------------------------------------
__global__ void k_final(const float* __restrict__ vis,
                        const float* __restrict__ txt,
                        const unsigned char* __restrict__ sel,
                        float* __restrict__ out) {
    const int total4 = B * C * HW / 4;     // 4,194,304
    int stride = gridDim.x * blockDim.x;
    for (int i = blockIdx.x * blockDim.x + threadIdx.x; i < total4; i += stride) {
        float4 v = ((const float4*)vis)[i];
        float4 t = ((const float4*)txt)[i];
        int idx = i << 2;                  // float index
        int b   = idx >> 20;               // / (C*HW)
        int hw  = idx & (HW - 1);
        uchar4 s = *(const uchar4*)(sel + (b << 12) + hw);
        float4 o;
        o.x = (s.x == 1) ? v.x : ((s.x == 2) ? t.x : 0.f);
        o.y = (s.y == 1) ? v.y : ((s.y == 2) ? t.y : 0.f);
        o.z = (s.z == 1) ? v.z : ((s.z == 2) ? t.z : 0.f);
        o.w = (s.w == 1) ? v.w : ((s.w == 2) ? t.w : 0.f);
        ((float4*)out)[i] = o;
    }
}

// ---------------------------------------------------------------------------
extern "C" void kernel_launch(void* const* d_in, const int* in_sizes, int n_in,
                              void* d_out, int out_size, void* d_ws, size_t ws_size,
                              hipStream_t stream) {
    const float* vis = (const float*)d_in[0];
    const float* txt = (const float*)d_in[1];
    const float* w1  = (const float*)d_in[2];
    const float* b1  = (const float*)d_in[3];
    const float* w2  = (const float*)d_in[4];
    const float* b2  = (const float*)d_in[5];

    float* out_enh      = (float*)d_out;                 // B*C*HW
    float* out_ent_vis  = out_enh + (size_t)B * C * HW;  // B*HW
    float* out_ent_text = out_ent_vis + B * HW;          // B*HW

    // workspace layout (floats)
    float* ws       = (float*)d_ws;
    float* pooled   = ws;                 //  8192
    float* cw       = ws + 8192;          //  8192
    float* se       = ws + 16384;         // 131072 (zeroed inside k_pooled)
    float* inv_norm = ws + 147456;        //     32
    float* thr      = ws + 147488;        //     32
    unsigned char* sel = (unsigned char*)(ws + 147520);  // 65536 bytes

    k_pooled  <<<2 * B * C, NTHREADS, 0, stream>>>(vis, txt, pooled, se);
    k_mlp     <<<2,         NTHREADS, 0, stream>>>(pooled, w1, b1, w2, b2, cw);
    k_se      <<<1024,      NTHREADS, 0, stream>>>(vis, txt, cw, se);
    k_stats   <<<2 * B,     NTHREADS, 0, stream>>>(se, inv_norm, thr);
    k_selwrite<<<B * HW / NTHREADS, NTHREADS, 0, stream>>>(se, inv_norm, thr,
                                                           out_ent_vis, out_ent_text, sel);
    k_final   <<<2048,      NTHREADS, 0, stream>>>(vis, txt, sel, out_enh);
}

// Round 4
// 263.964 us; speedup vs baseline: 1.1681x; 1.0132x over previous
//
#include <hip/hip_runtime.h>
#include <math.h>

#define B 16
#define C 256
#define HW 4096              // 64*64
#define EPSE 1e-9f
#define NTHREADS 256
#define CCHUNK 16            // channels per k_se block (16 chunks)

typedef float nfloat4 __attribute__((ext_vector_type(4)));

__device__ __forceinline__ void nt_store4(float* p, float4 v) {
    nfloat4 nv = { v.x, v.y, v.z, v.w };
    __builtin_nontemporal_store(nv, (nfloat4*)p);
}

__device__ __forceinline__ float fast_rcp(float x) { return __builtin_amdgcn_rcpf(x); }

// ent(x) = log(p+eps) - (1-p)*log(1-p+eps), p = sigmoid(x)
__device__ __forceinline__ float entf(float x) {
    float e  = __expf(-x);
    float p  = fast_rcp(1.f + e);
    float l1 = __logf(p + EPSE);
    float q  = 1.f - p;
    float l2 = __logf(q + EPSE);
    return fmaf(-q, l2, l1);
}

// ---------------------------------------------------------------------------
// Kernel 1: pooled[f][b][c] = mean over HW of feat[b][c][:]
// One WAVE per row: 16 independent float4 loads/lane, no LDS, no barrier.
// grid = 2048 blocks (4 waves each -> 8192 rows), 256 threads
// First 128 blocks also zero the se accumulator (ws is poisoned 0xAA).
// ---------------------------------------------------------------------------
__global__ void k_pooled(const float* __restrict__ vis,
                         const float* __restrict__ txt,
                         float* __restrict__ pooled,
                         float* __restrict__ se) {
    int blk = blockIdx.x;
    if (blk < 128) {                   // zero se: 128 blocks * 1024 floats
        ((float4*)se)[blk * NTHREADS + threadIdx.x] = make_float4(0.f, 0.f, 0.f, 0.f);
    }
    int wave = (blk << 2) | (threadIdx.x >> 6);   // [0, 8192) = row id
    int lane = threadIdx.x & 63;
    int f    = wave >> 12;
    int bc   = wave & (B * C - 1);
    const float4* src = (const float4*)((f == 0 ? vis : txt) + (size_t)bc * HW);

    float s0 = 0.f, s1 = 0.f, s2 = 0.f, s3 = 0.f;
    #pragma unroll
    for (int k = 0; k < 16; k += 4) {
        float4 a = src[lane + (k + 0) * 64];
        float4 b = src[lane + (k + 1) * 64];
        float4 c = src[lane + (k + 2) * 64];
        float4 d = src[lane + (k + 3) * 64];
        s0 += a.x + a.y + a.z + a.w;
        s1 += b.x + b.y + b.z + b.w;
        s2 += c.x + c.y + c.z + c.w;
        s3 += d.x + d.y + d.z + d.w;
    }
    float s = (s0 + s1) + (s2 + s3);
    for (int off = 32; off > 0; off >>= 1) s += __shfl_down(s, off);
    if (lane == 0) pooled[wave] = s * (1.0f / HW);
}

// ---------------------------------------------------------------------------
// Kernel 2: tiny MLP  cw = sigmoid(relu(pooled@w1 + b1)@w2 + b2)
// grid = 2 blocks (one per feat), 256 threads
// ---------------------------------------------------------------------------
__global__ void k_mlp(const float* __restrict__ pooled,
                      const float* __restrict__ w1, const float* __restrict__ b1,
                      const float* __restrict__ w2, const float* __restrict__ b2,
                      float* __restrict__ cw) {
    __shared__ float pl[B * C];     // 16 KB
    __shared__ float h[B * 64];     // 4 KB
    int f = blockIdx.x;
    const float* P = pooled + f * B * C;
    for (int i = threadIdx.x; i < B * C; i += NTHREADS) pl[i] = P[i];
    __syncthreads();
    for (int o = threadIdx.x; o < B * 64; o += NTHREADS) {
        int b = o >> 6, j = o & 63;
        float acc = b1[j];
        for (int c = 0; c < C; ++c) acc = fmaf(pl[b * C + c], w1[c * 64 + j], acc);
        h[o] = fmaxf(acc, 0.f);
    }
    __syncthreads();
    for (int o = threadIdx.x; o < B * C; o += NTHREADS) {
        int b = o >> 8, c2 = o & 255;
        float acc = b2[c2];
        for (int j = 0; j < 64; ++j) acc = fmaf(h[b * 64 + j], w2[j * 256 + c2], acc);
        cw[f * B * C + o] = fast_rcp(1.f + __expf(-acc));
    }
}

// ---------------------------------------------------------------------------
// Kernel 3: se[f][b][hw] += sum_{c in chunk} ent(feat[b][c][hw]) * cw[f][b][c]
// grid = 2 * 16b * 4 tiles * 16 c-chunks = 2048 blocks, 256 threads
// ---------------------------------------------------------------------------
__global__ void k_se(const float* __restrict__ vis,
                     const float* __restrict__ txt,
                     const float* __restrict__ cw,
                     float* __restrict__ se) {
    int bx   = blockIdx.x;             // [0, 2048)
    int cc   = bx & 15;                // c-chunk (16 channels)
    int tile = (bx >> 4) & 3;          // 1024-hw tile
    int b    = (bx >> 6) & 15;
    int f    = bx >> 10;
    const float* src = (f == 0 ? vis : txt)
                       + (size_t)b * C * HW + (size_t)cc * CCHUNK * HW
                       + tile * 1024 + threadIdx.x * 4;

    __shared__ float cwl[CCHUNK];
    if (threadIdx.x < CCHUNK)
        cwl[threadIdx.x] = cw[f * B * C + b * C + cc * CCHUNK + threadIdx.x];
    __syncthreads();

    float4 acc = make_float4(0.f, 0.f, 0.f, 0.f);
    #pragma unroll 4
    for (int c = 0; c < CCHUNK; ++c) {
        float4 x = *(const float4*)(src + (size_t)c * HW);
        float w = cwl[c];
        acc.x = fmaf(entf(x.x), w, acc.x);
        acc.y = fmaf(entf(x.y), w, acc.y);
        acc.z = fmaf(entf(x.z), w, acc.z);
        acc.w = fmaf(entf(x.w), w, acc.w);
    }
    float* dst = se + (f * B + b) * HW + tile * 1024 + threadIdx.x * 4;
    atomicAdd(dst + 0, acc.x);
    atomicAdd(dst + 1, acc.y);
    atomicAdd(dst + 2, acc.z);
    atomicAdd(dst + 3, acc.w);
}

// ---------------------------------------------------------------------------
// Kernel 4: per-(f,b) stats over se: inv_norm = 1/max(||se||2, 1e-12),
//           thr = 0.5 * mean(se)   (scale-invariant mask threshold)
// grid = 2*B = 32 blocks, 256 threads
// ---------------------------------------------------------------------------
__global__ void k_stats(const float* __restrict__ se,
                        float* __restrict__ inv_norm,
                        float* __restrict__ thr) {
    int fb = blockIdx.x;               // [0, 32)
    const float4* s4 = (const float4*)(se + fb * HW);
    float s = 0.f, ss = 0.f;
    #pragma unroll
    for (int i = threadIdx.x; i < HW / 4; i += NTHREADS) {
        float4 v = s4[i];
        s  += v.x + v.y + v.z + v.w;
        ss = fmaf(v.x, v.x, ss); ss = fmaf(v.y, v.y, ss);
        ss = fmaf(v.z, v.z, ss); ss = fmaf(v.w, v.w, ss);
    }
    for (int off = 32; off > 0; off >>= 1) {
        s  += __shfl_down(s, off);
        ss += __shfl_down(ss, off);
    }
    __shared__ float sm[8];
    if ((threadIdx.x & 63) == 0) {
        sm[(threadIdx.x >> 6) * 2]     = s;
        sm[(threadIdx.x >> 6) * 2 + 1] = ss;
    }
    __syncthreads();
    if (threadIdx.x == 0) {
        float st  = sm[0] + sm[2] + sm[4] + sm[6];
        float sst = sm[1] + sm[3] + sm[5] + sm[7];
        inv_norm[fb] = 1.f / fmaxf(sqrtf(sst), 1e-12f);
        thr[fb]      = 0.5f * (st * (1.0f / HW));
    }
}

// ---------------------------------------------------------------------------
// Kernel 5 (fused selwrite+final):
//   sel computed inline from se + thr; entropy maps written by cg==0 blocks;
//   enhanced = vl ? vis : (tl ? text : 0) with nontemporal stores.
// grid = 16b * 4 tiles * 16 c-groups = 1024 blocks, 256 threads
// ---------------------------------------------------------------------------
__global__ void k_final(const float* __restrict__ vis,
                        const float* __restrict__ txt,
                        const float* __restrict__ se,
                        const float* __restrict__ inv_norm,
                        const float* __restrict__ thr,
                        float* __restrict__ out_enh,
                        float* __restrict__ out_ent_vis,
                        float* __restrict__ out_ent_text) {
    int bx   = blockIdx.x;             // [0, 1024)
    int cg   = bx & 15;                // 16-channel group
    int tile = (bx >> 4) & 3;          // 1024-hw tile
    int b    = bx >> 6;

    int hw   = tile * 1024 + threadIdx.x * 4;
    int mapi = b * HW + hw;            // index into [B,HW] maps

    float4 sv = *(const float4*)(se + mapi);             // f=0 slab
    float4 st = *(const float4*)(se + B * HW + mapi);    // f=1 slab
    float tv = thr[b], tt = thr[B + b];

    if (cg == 0) {       // write normalized entropy maps once per (b,hw)
        float inv = inv_norm[b], int_ = inv_norm[B + b];
        float4 ov = make_float4(sv.x * inv, sv.y * inv, sv.z * inv, sv.w * inv);
        float4 ot = make_float4(st.x * int_, st.y * int_, st.z * int_, st.w * int_);
        nt_store4(out_ent_vis + mapi, ov);
        nt_store4(out_ent_text + mapi, ot);
    }

    int m0 = sv.x < tv ? 1 : (st.x < tt ? 2 : 0);
    int m1 = sv.y < tv ? 1 : (st.y < tt ? 2 : 0);
    int m2 = sv.z < tv ? 1 : (st.z < tt ? 2 : 0);
    int m3 = sv.w < tv ? 1 : (st.w < tt ? 2 : 0);

    size_t base = (size_t)b * C * HW + (size_t)cg * 16 * HW + hw;
    #pragma unroll 4
    for (int c = 0; c < 16; ++c) {
        size_t idx = base + (size_t)c * HW;
        float4 v = *(const float4*)(vis + idx);
        float4 t = *(const float4*)(txt + idx);
        float4 o;
        o.x = (m0 == 1) ? v.x : ((m0 == 2) ? t.x : 0.f);
        o.y = (m1 == 1) ? v.y : ((m1 == 2) ? t.y : 0.f);
        o.z = (m2 == 1) ? v.z : ((m2 == 2) ? t.z : 0.f);
        o.w = (m3 == 1) ? v.w : ((m3 == 2) ? t.w : 0.f);
        nt_store4(out_enh + idx, o);
    }
}

// ---------------------------------------------------------------------------
extern "C" void kernel_launch(void* const* d_in, const int* in_sizes, int n_in,
                              void* d_out, int out_size, void* d_ws, size_t ws_size,
                              hipStream_t stream) {
    const float* vis = (const float*)d_in[0];
    const float* txt = (const float*)d_in[1];
    const float* w1  = (const float*)d_in[2];
    const float* b1  = (const float*)d_in[3];
    const float* w2  = (const float*)d_in[4];
    const float* b2  = (const float*)d_in[5];

    float* out_enh      = (float*)d_out;                 // B*C*HW
    float* out_ent_vis  = out_enh + (size_t)B * C * HW;  // B*HW
    float* out_ent_text = out_ent_vis + B * HW;          // B*HW

    // workspace layout (floats)
    float* ws       = (float*)d_ws;
    float* pooled   = ws;                 //  8192
    float* cw       = ws + 8192;          //  8192
    float* se       = ws + 16384;         // 131072 (zeroed inside k_pooled)
    float* inv_norm = ws + 147456;        //     32
    float* thr      = ws + 147488;        //     32

    k_pooled<<<2048, NTHREADS, 0, stream>>>(vis, txt, pooled, se);
    k_mlp   <<<2,    NTHREADS, 0, stream>>>(pooled, w1, b1, w2, b2, cw);
    k_se    <<<2048, NTHREADS, 0, stream>>>(vis, txt, cw, se);
    k_stats <<<32,   NTHREADS, 0, stream>>>(se, inv_norm, thr);
    k_final <<<1024, NTHREADS, 0, stream>>>(vis, txt, se, inv_norm, thr,
                                            out_enh, out_ent_vis, out_ent_text);
}

// Round 5
// 262.246 us; speedup vs baseline: 1.1757x; 1.0066x over previous
//
#include <hip/hip_runtime.h>
#include <math.h>

#define B 16
#define C 256
#define HW 4096              // 64*64
#define EPSE 1e-9f
#define NTHREADS 256
#define CCHUNK 16            // channels per k_se block

typedef float nfloat4 __attribute__((ext_vector_type(4)));

__device__ __forceinline__ void nt_store4(float* p, float4 v) {
    nfloat4 nv = { v.x, v.y, v.z, v.w };
    __builtin_nontemporal_store(nv, (nfloat4*)p);
}

__device__ __forceinline__ float fast_rcp(float x) { return __builtin_amdgcn_rcpf(x); }

// ent(x) = log(p+eps) - (1-p)*log(1-p+eps), p = sigmoid(x)
__device__ __forceinline__ float entf(float x) {
    float e  = __expf(-x);
    float p  = fast_rcp(1.f + e);
    float l1 = __logf(p + EPSE);
    float q  = 1.f - p;
    float l2 = __logf(q + EPSE);
    return fmaf(-q, l2, l1);
}

// ---------------------------------------------------------------------------
// Kernel 1: pooled[f][b][c] = mean over HW of feat[b][c][:]
// One BLOCK per row; each thread reads 64 B CONTIGUOUS:
// 4 dwordx4 off one base reg, immediate offsets 0/16/32/48 -> no addr math,
// 4 independent loads in flight, ~20 VGPRs -> 8 waves/SIMD.
// grid = 8192 blocks, 256 threads. First 128 blocks zero se.
// ---------------------------------------------------------------------------
__global__ void k_pooled(const float* __restrict__ vis,
                         const float* __restrict__ txt,
                         float* __restrict__ pooled,
                         float* __restrict__ se) {
    int row = blockIdx.x;              // [0, 8192)
    if (row < 128) {                   // zero se: 128 blocks * 1024 floats
        ((float4*)se)[row * NTHREADS + threadIdx.x] = make_float4(0.f, 0.f, 0.f, 0.f);
    }
    int f  = row >> 12;
    int bc = row & (B * C - 1);
    const float* src = (f == 0 ? vis : txt) + (size_t)bc * HW + threadIdx.x * 16;

    float4 a = *(const float4*)(src + 0);
    float4 b = *(const float4*)(src + 4);
    float4 c = *(const float4*)(src + 8);
    float4 d = *(const float4*)(src + 12);
    float s = (((a.x + a.y) + (a.z + a.w)) + ((b.x + b.y) + (b.z + b.w)))
            + (((c.x + c.y) + (c.z + c.w)) + ((d.x + d.y) + (d.z + d.w)));

    for (int off = 32; off > 0; off >>= 1) s += __shfl_down(s, off);
    __shared__ float sm[4];
    if ((threadIdx.x & 63) == 0) sm[threadIdx.x >> 6] = s;
    __syncthreads();
    if (threadIdx.x == 0)
        pooled[row] = (sm[0] + sm[1] + sm[2] + sm[3]) * (1.0f / HW);
}

// ---------------------------------------------------------------------------
// Kernel 2: tiny MLP  cw = sigmoid(relu(pooled@w1 + b1)@w2 + b2)
// grid = 2 blocks (one per feat), 256 threads
// ---------------------------------------------------------------------------
__global__ void k_mlp(const float* __restrict__ pooled,
                      const float* __restrict__ w1, const float* __restrict__ b1,
                      const float* __restrict__ w2, const float* __restrict__ b2,
                      float* __restrict__ cw) {
    __shared__ float pl[B * C];     // 16 KB
    __shared__ float h[B * 64];     // 4 KB
    int f = blockIdx.x;
    const float* P = pooled + f * B * C;
    for (int i = threadIdx.x; i < B * C; i += NTHREADS) pl[i] = P[i];
    __syncthreads();
    for (int o = threadIdx.x; o < B * 64; o += NTHREADS) {
        int b = o >> 6, j = o & 63;
        float acc = b1[j];
        for (int c = 0; c < C; ++c) acc = fmaf(pl[b * C + c], w1[c * 64 + j], acc);
        h[o] = fmaxf(acc, 0.f);
    }
    __syncthreads();
    for (int o = threadIdx.x; o < B * C; o += NTHREADS) {
        int b = o >> 8, c2 = o & 255;
        float acc = b2[c2];
        for (int j = 0; j < 64; ++j) acc = fmaf(h[b * 64 + j], w2[j * 256 + c2], acc);
        cw[f * B * C + o] = fast_rcp(1.f + __expf(-acc));
    }
}

// ---------------------------------------------------------------------------
// Kernel 3: se[f][b][hw] += sum_{c in chunk} ent(feat[b][c][hw]) * cw[f][b][c]
// grid = 2048 blocks, 256 threads; loads batched 8-deep (xs[8]) so 8
// independent dwordx4 are in flight before any trans-op consumption.
// ---------------------------------------------------------------------------
__global__ void __launch_bounds__(NTHREADS, 4)
k_se(const float* __restrict__ vis,
     const float* __restrict__ txt,
     const float* __restrict__ cw,
     float* __restrict__ se) {
    int bx   = blockIdx.x;             // [0, 2048)
    int cc   = bx & 15;                // c-chunk (16 channels)
    int tile = (bx >> 4) & 3;          // 1024-hw tile
    int b    = (bx >> 6) & 15;
    int f    = bx >> 10;
    const float* src = (f == 0 ? vis : txt)
                       + (size_t)b * C * HW + (size_t)cc * CCHUNK * HW
                       + tile * 1024 + threadIdx.x * 4;

    __shared__ float cwl[CCHUNK];
    if (threadIdx.x < CCHUNK)
        cwl[threadIdx.x] = cw[f * B * C + b * C + cc * CCHUNK + threadIdx.x];
    __syncthreads();

    float4 acc = make_float4(0.f, 0.f, 0.f, 0.f);
    #pragma unroll
    for (int g = 0; g < CCHUNK / 8; ++g) {
        float4 xs[8];
        #pragma unroll
        for (int j = 0; j < 8; ++j)
            xs[j] = *(const float4*)(src + (size_t)(g * 8 + j) * HW);
        #pragma unroll
        for (int j = 0; j < 8; ++j) {
            float w = cwl[g * 8 + j];
            acc.x = fmaf(entf(xs[j].x), w, acc.x);
            acc.y = fmaf(entf(xs[j].y), w, acc.y);
            acc.z = fmaf(entf(xs[j].z), w, acc.z);
            acc.w = fmaf(entf(xs[j].w), w, acc.w);
        }
    }
    float* dst = se + (f * B + b) * HW + tile * 1024 + threadIdx.x * 4;
    atomicAdd(dst + 0, acc.x);
    atomicAdd(dst + 1, acc.y);
    atomicAdd(dst + 2, acc.z);
    atomicAdd(dst + 3, acc.w);
}

// ---------------------------------------------------------------------------
// Kernel 4: per-(f,b) stats over se: inv_norm = 1/max(||se||2, 1e-12),
//           thr = 0.5 * mean(se)
// grid = 2*B = 32 blocks, 256 threads
// ---------------------------------------------------------------------------
__global__ void k_stats(const float* __restrict__ se,
                        float* __restrict__ inv_norm,
                        float* __restrict__ thr) {
    int fb = blockIdx.x;               // [0, 32)
    const float4* s4 = (const float4*)(se + fb * HW);
    float s = 0.f, ss = 0.f;
    #pragma unroll
    for (int i = threadIdx.x; i < HW / 4; i += NTHREADS) {
        float4 v = s4[i];
        s  += v.x + v.y + v.z + v.w;
        ss = fmaf(v.x, v.x, ss); ss = fmaf(v.y, v.y, ss);
        ss = fmaf(v.z, v.z, ss); ss = fmaf(v.w, v.w, ss);
    }
    for (int off = 32; off > 0; off >>= 1) {
        s  += __shfl_down(s, off);
        ss += __shfl_down(ss, off);
    }
    __shared__ float sm[8];
    if ((threadIdx.x & 63) == 0) {
        sm[(threadIdx.x >> 6) * 2]     = s;
        sm[(threadIdx.x >> 6) * 2 + 1] = ss;
    }
    __syncthreads();
    if (threadIdx.x == 0) {
        float st  = sm[0] + sm[2] + sm[4] + sm[6];
        float sst = sm[1] + sm[3] + sm[5] + sm[7];
        inv_norm[fb] = 1.f / fmaxf(sqrtf(sst), 1e-12f);
        thr[fb]      = 0.5f * (st * (1.0f / HW));
    }
}

// ---------------------------------------------------------------------------
// Kernel 5 (fused selwrite+final): loads batched 8-deep per feat.
// grid = 16b * 4 tiles * 16 c-groups = 1024 blocks, 256 threads
// ---------------------------------------------------------------------------
__global__ void __launch_bounds__(NTHREADS, 4)
k_final(const float* __restrict__ vis,
        const float* __restrict__ txt,
        const float* __restrict__ se,
        const float* __restrict__ inv_norm,
        const float* __restrict__ thr,
        float* __restrict__ out_enh,
        float* __restrict__ out_ent_vis,
        float* __restrict__ out_ent_text) {
    int bx   = blockIdx.x;             // [0, 1024)
    int cg   = bx & 15;                // 16-channel group
    int tile = (bx >> 4) & 3;          // 1024-hw tile
    int b    = bx >> 6;

    int hw   = tile * 1024 + threadIdx.x * 4;
    int mapi = b * HW + hw;            // index into [B,HW] maps

    float4 sv = *(const float4*)(se + mapi);             // f=0 slab
    float4 st = *(const float4*)(se + B * HW + mapi);    // f=1 slab
    float tv = thr[b], tt = thr[B + b];

    if (cg == 0) {       // write normalized entropy maps once per (b,hw)
        float inv = inv_norm[b], int_ = inv_norm[B + b];
        float4 ov = make_float4(sv.x * inv, sv.y * inv, sv.z * inv, sv.w * inv);
        float4 ot = make_float4(st.x * int_, st.y * int_, st.z * int_, st.w * int_);
        nt_store4(out_ent_vis + mapi, ov);
        nt_store4(out_ent_text + mapi, ot);
    }

    int m0 = sv.x < tv ? 1 : (st.x < tt ? 2 : 0);
    int m1 = sv.y < tv ? 1 : (st.y < tt ? 2 : 0);
    int m2 = sv.z < tv ? 1 : (st.z < tt ? 2 : 0);
    int m3 = sv.w < tv ? 1 : (st.w < tt ? 2 : 0);

    size_t base = (size_t)b * C * HW + (size_t)cg * 16 * HW + hw;
    #pragma unroll
    for (int g = 0; g < 2; ++g) {
        float4 vv[8], tt4[8];
        #pragma unroll
        for (int c = 0; c < 8; ++c) {
            size_t idx = base + (size_t)(g * 8 + c) * HW;
            vv[c]  = *(const float4*)(vis + idx);
            tt4[c] = *(const float4*)(txt + idx);
        }
        #pragma unroll
        for (int c = 0; c < 8; ++c) {
            size_t idx = base + (size_t)(g * 8 + c) * HW;
            float4 o;
            o.x = (m0 == 1) ? vv[c].x : ((m0 == 2) ? tt4[c].x : 0.f);
            o.y = (m1 == 1) ? vv[c].y : ((m1 == 2) ? tt4[c].y : 0.f);
            o.z = (m2 == 1) ? vv[c].z : ((m2 == 2) ? tt4[c].z : 0.f);
            o.w = (m3 == 1) ? vv[c].w : ((m3 == 2) ? tt4[c].w : 0.f);
            nt_store4(out_enh + idx, o);
        }
    }
}

// ---------------------------------------------------------------------------
extern "C" void kernel_launch(void* const* d_in, const int* in_sizes, int n_in,
                              void* d_out, int out_size, void* d_ws, size_t ws_size,
                              hipStream_t stream) {
    const float* vis = (const float*)d_in[0];
    const float* txt = (const float*)d_in[1];
    const float* w1  = (const float*)d_in[2];
    const float* b1  = (const float*)d_in[3];
    const float* w2  = (const float*)d_in[4];
    const float* b2  = (const float*)d_in[5];

    float* out_enh      = (float*)d_out;                 // B*C*HW
    float* out_ent_vis  = out_enh + (size_t)B * C * HW;  // B*HW
    float* out_ent_text = out_ent_vis + B * HW;          // B*HW

    // workspace layout (floats)
    float* ws       = (float*)d_ws;
    float* pooled   = ws;                 //  8192
    float* cw       = ws + 8192;          //  8192
    float* se       = ws + 16384;         // 131072 (zeroed inside k_pooled)
    float* inv_norm = ws + 147456;        //     32
    float* thr      = ws + 147488;        //     32

    k_pooled<<<8192, NTHREADS, 0, stream>>>(vis, txt, pooled, se);
    k_mlp   <<<2,    NTHREADS, 0, stream>>>(pooled, w1, b1, w2, b2, cw);
    k_se    <<<2048, NTHREADS, 0, stream>>>(vis, txt, cw, se);
    k_stats <<<32,   NTHREADS, 0, stream>>>(se, inv_norm, thr);
    k_final <<<1024, NTHREADS, 0, stream>>>(vis, txt, se, inv_norm, thr,
                                            out_enh, out_ent_vis, out_ent_text);
}